// Round 1
// baseline (2035.280 us; speedup 1.0000x reference)
//
#include <hip/hip_runtime.h>
#include <math.h>

#define BB 2
#define NN 8192
#define DD 512   // IN_DIM == ATT_DIM == 512

static const float INV_SCALE = 0.04419417382415922f; // 1/sqrt(512)

// ---------------------------------------------------------------------------
// Generic tiled f32 GEMM: C = A @ B, all row-major, lda=K, ldb=N.
// BM=BN=128, BK=16, 256 threads, 8x8 accumulators per thread.
// All problem dims are multiples of the tiles -> no bounds checks.
// MODE 0: plain store to C (ldc = N), batched via blockIdx.z strides.
// MODE 1: qk split epilogue: cols [0,512) -> C (q, ldc=512),
//         cols [512,1024) -> C2 (k*mask, ldc=512). N must be 1024.
// ---------------------------------------------------------------------------
template <int MODE>
__global__ __launch_bounds__(256) void gemm_f32(
    const float* __restrict__ A, const float* __restrict__ B,
    float* __restrict__ C, float* __restrict__ C2,
    const float* __restrict__ mask,
    int M, int N, int K,
    long strideA, long strideB, long strideC)
{
    __shared__ float As[16][128];  // transposed: As[k][m]
    __shared__ float Bs[16][128];

    const int bz = blockIdx.z;
    A += (long)bz * strideA;
    B += (long)bz * strideB;
    if (MODE == 0) C += (long)bz * strideC;

    const int m0 = blockIdx.x * 128;
    const int n0 = blockIdx.y * 128;
    const int t  = threadIdx.x;
    const int ty = t >> 4;   // 0..15
    const int tx = t & 15;   // 0..15

    float acc[8][8];
#pragma unroll
    for (int i = 0; i < 8; ++i)
#pragma unroll
        for (int j = 0; j < 8; ++j) acc[i][j] = 0.f;

    for (int k0 = 0; k0 < K; k0 += 16) {
        // Load A tile (128x16) -> As transposed. 2 float4 per thread.
#pragma unroll
        for (int u = 0; u < 2; ++u) {
            int idx = t + u * 256;          // 0..511
            int row = idx >> 2;             // 0..127
            int kq  = (idx & 3) << 2;       // 0,4,8,12
            const float4 a4 = *(const float4*)(A + (long)(m0 + row) * K + k0 + kq);
            As[kq + 0][row] = a4.x;
            As[kq + 1][row] = a4.y;
            As[kq + 2][row] = a4.z;
            As[kq + 3][row] = a4.w;
        }
        // Load B tile (16x128). 1 float4 per thread x2.
#pragma unroll
        for (int u = 0; u < 2; ++u) {
            int idx = t + u * 256;
            int kk  = idx >> 5;             // 0..15
            int c4  = (idx & 31) << 2;      // 0..124
            *(float4*)(&Bs[kk][c4]) =
                *(const float4*)(B + (long)(k0 + kk) * N + n0 + c4);
        }
        __syncthreads();

#pragma unroll
        for (int kk = 0; kk < 16; ++kk) {
            float a[8], b[8];
            *(float4*)(a)     = *(const float4*)(&As[kk][ty * 8]);
            *(float4*)(a + 4) = *(const float4*)(&As[kk][ty * 8 + 4]);
            *(float4*)(b)     = *(const float4*)(&Bs[kk][tx * 8]);
            *(float4*)(b + 4) = *(const float4*)(&Bs[kk][tx * 8 + 4]);
#pragma unroll
            for (int i = 0; i < 8; ++i)
#pragma unroll
                for (int j = 0; j < 8; ++j)
                    acc[i][j] += a[i] * b[j];
        }
        __syncthreads();
    }

    if (MODE == 0) {
#pragma unroll
        for (int i = 0; i < 8; ++i) {
            long r = m0 + ty * 8 + i;
            float* Crow = C + r * (long)N + n0 + tx * 8;
            *(float4*)(Crow)     = make_float4(acc[i][0], acc[i][1], acc[i][2], acc[i][3]);
            *(float4*)(Crow + 4) = make_float4(acc[i][4], acc[i][5], acc[i][6], acc[i][7]);
        }
    } else {
        const bool isq = (n0 < 512);   // block never straddles the 512 boundary
#pragma unroll
        for (int i = 0; i < 8; ++i) {
            long r  = m0 + ty * 8 + i;
            int col = n0 + tx * 8 - (isq ? 0 : 512);
            float mk = isq ? 1.f : mask[r];
            float* Drow = (isq ? C : C2) + r * 512L + col;
            *(float4*)(Drow)     = make_float4(acc[i][0] * mk, acc[i][1] * mk,
                                               acc[i][2] * mk, acc[i][3] * mk);
            *(float4*)(Drow + 4) = make_float4(acc[i][4] * mk, acc[i][5] * mk,
                                               acc[i][6] * mk, acc[i][7] * mk);
        }
    }
}

// ---------------------------------------------------------------------------
// w[row] = inv_scale * mask[row] * dot(q[row,:], agg[row,:])   (512 elements)
// One 128-thread block per row; each thread one float4.
// ---------------------------------------------------------------------------
__global__ __launch_bounds__(128) void wdot_k(
    const float* __restrict__ q, const float* __restrict__ agg,
    const float* __restrict__ mask, float* __restrict__ w)
{
    const int row = blockIdx.x;
    const int t = threadIdx.x;
    const float4 qv = ((const float4*)(q   + (long)row * 512))[t];
    const float4 av = ((const float4*)(agg + (long)row * 512))[t];
    float s = qv.x * av.x + qv.y * av.y + qv.z * av.z + qv.w * av.w;
#pragma unroll
    for (int o = 32; o > 0; o >>= 1) s += __shfl_down(s, o);
    __shared__ float red[2];
    if ((t & 63) == 0) red[t >> 6] = s;
    __syncthreads();
    if (t == 0) w[row] = (red[0] + red[1]) * INV_SCALE * mask[row];
}

// ---------------------------------------------------------------------------
// Softmax over the N dimension per batch: p = softmax(w[b, :])
// One 1024-thread block per batch.
// ---------------------------------------------------------------------------
__global__ __launch_bounds__(1024) void softmax_k(
    const float* __restrict__ w, float* __restrict__ p)
{
    const int b = blockIdx.x;
    const float* wr = w + (long)b * NN;
    float* pr = p + (long)b * NN;
    const int t = threadIdx.x;
    __shared__ float red[16];
    __shared__ float bmax, bsum;

    float m = -3.4e38f;
    for (int i = t; i < NN; i += 1024) m = fmaxf(m, wr[i]);
#pragma unroll
    for (int o = 32; o > 0; o >>= 1) m = fmaxf(m, __shfl_down(m, o));
    if ((t & 63) == 0) red[t >> 6] = m;
    __syncthreads();
    if (t == 0) {
        float mm = red[0];
        for (int i = 1; i < 16; ++i) mm = fmaxf(mm, red[i]);
        bmax = mm;
    }
    __syncthreads();
    const float M = bmax;

    float s = 0.f;
    for (int i = t; i < NN; i += 1024) s += expf(wr[i] - M);
#pragma unroll
    for (int o = 32; o > 0; o >>= 1) s += __shfl_down(s, o);
    __syncthreads();
    if ((t & 63) == 0) red[t >> 6] = s;
    __syncthreads();
    if (t == 0) {
        float ss = 0.f;
        for (int i = 0; i < 16; ++i) ss += red[i];
        bsum = ss;
    }
    __syncthreads();
    const float invS = 1.f / bsum;

    for (int i = t; i < NN; i += 1024) pr[i] = expf(wr[i] - M) * invS;
}

// ---------------------------------------------------------------------------
// out[row, d] = p[row] * v[row, d]  (float4 elementwise)
// ---------------------------------------------------------------------------
__global__ __launch_bounds__(256) void scale_k(
    const float* __restrict__ v, const float* __restrict__ p,
    float* __restrict__ out)
{
    const long i = (long)blockIdx.x * 256 + threadIdx.x;  // float4 index
    const int row = (int)(i >> 7);                        // 128 float4 per row
    const float pv = p[row];
    float4 vv = ((const float4*)v)[i];
    vv.x *= pv; vv.y *= pv; vv.z *= pv; vv.w *= pv;
    ((float4*)out)[i] = vv;
}

// ---------------------------------------------------------------------------
extern "C" void kernel_launch(void* const* d_in, const int* in_sizes, int n_in,
                              void* d_out, int out_size, void* d_ws, size_t ws_size,
                              hipStream_t stream)
{
    const float* X    = (const float*)d_in[0];  // (B,N,512)
    const float* adj  = (const float*)d_in[1];  // (B,N,N)
    const float* mask = (const float*)d_in[2];  // (B,N)
    const float* Wqk  = (const float*)d_in[3];  // (512,1024)
    const float* Wv   = (const float*)d_in[4];  // (512,512)
    float* out = (float*)d_out;                 // (B,N,512)

    const long SZ = (long)BB * NN * DD;         // 8,388,608 floats
    float* ws = (float*)d_ws;
    float* q_buf   = ws;                        // B*N*512
    float* km_buf  = ws + SZ;                   // B*N*512 (k * mask)
    float* v_buf   = ws + 2 * SZ;               // B*N*512
    float* agg_buf = ws + 3 * SZ;               // B*N*512
    float* w_buf   = ws + 4 * SZ;               // B*N
    float* p_buf   = w_buf + (long)BB * NN;     // B*N
    // total: 4*SZ + 2*16384 floats = 134.3 MB

    const int M = BB * NN;  // 16384 flat rows

    // 1) qk = X @ Wqk, split into q and k*mask
    gemm_f32<1><<<dim3(M / 128, 1024 / 128, 1), 256, 0, stream>>>(
        X, Wqk, q_buf, km_buf, mask, M, 1024, 512, 0, 0, 0);

    // 2) v = X @ Wv
    gemm_f32<0><<<dim3(M / 128, 512 / 128, 1), 256, 0, stream>>>(
        X, Wv, v_buf, nullptr, nullptr, M, 512, 512, 0, 0, 0);

    // 3) agg[b] = adj[b] @ km[b]   (batched over z)
    gemm_f32<0><<<dim3(NN / 128, 512 / 128, BB), 256, 0, stream>>>(
        adj, km_buf, agg_buf, nullptr, nullptr, NN, 512, NN,
        (long)NN * NN, (long)NN * 512, (long)NN * 512);

    // 4) w = inv_scale * mask * rowdot(q, agg)
    wdot_k<<<M, 128, 0, stream>>>(q_buf, agg_buf, mask, w_buf);

    // 5) p = softmax(w) over N, per batch
    softmax_k<<<BB, 1024, 0, stream>>>(w_buf, p_buf);

    // 6) out = p * v
    scale_k<<<(int)(SZ / 4 / 256), 256, 0, stream>>>(v_buf, p_buf, out);
}

// Round 2
// 553.703 us; speedup vs baseline: 3.6758x; 3.6758x over previous
//
#include <hip/hip_runtime.h>
#include <math.h>

#define BB 2
#define NN 8192
#define DD 512

static const float INV_SCALE = 0.04419417382415922f; // 1/sqrt(512)

typedef short s16x8 __attribute__((ext_vector_type(8)));
typedef float f32x4 __attribute__((ext_vector_type(4)));

#define AS1 __attribute__((address_space(1)))
#define AS3 __attribute__((address_space(3)))

__device__ __forceinline__ unsigned short bfbits(__bf16 h) {
    return __builtin_bit_cast(unsigned short, h);
}

__device__ __forceinline__ void gll16(const void* g, void* l) {
    __builtin_amdgcn_global_load_lds((const AS1 unsigned int*)g, (AS3 unsigned int*)l, 16, 0, 0);
}

// ---------------------------------------------------------------------------
// convX: X f32 -> Xhi, Xlo bf16 (hi = rne(x), lo = rne(x - hi))
// ---------------------------------------------------------------------------
__global__ __launch_bounds__(256) void convx_k(
    const float* __restrict__ X, unsigned short* __restrict__ Xhi,
    unsigned short* __restrict__ Xlo)
{
    long i = (long)blockIdx.x * 256 + threadIdx.x;   // float4 index
    float4 x = ((const float4*)X)[i];
    __bf16 h0 = (__bf16)x.x, h1 = (__bf16)x.y, h2 = (__bf16)x.z, h3 = (__bf16)x.w;
    ushort4 hi4 = make_ushort4(bfbits(h0), bfbits(h1), bfbits(h2), bfbits(h3));
    __bf16 l0 = (__bf16)(x.x - (float)h0), l1 = (__bf16)(x.y - (float)h1);
    __bf16 l2 = (__bf16)(x.z - (float)h2), l3 = (__bf16)(x.w - (float)h3);
    ushort4 lo4 = make_ushort4(bfbits(l0), bfbits(l1), bfbits(l2), bfbits(l3));
    ((ushort4*)Xhi)[i] = hi4;
    ((ushort4*)Xlo)[i] = lo4;
}

// ---------------------------------------------------------------------------
// convW: Wqk (512x1024) -> WqkT hi/lo (1024x512 bf16); Wv (512x512) -> WvT hi/lo
// ---------------------------------------------------------------------------
__global__ __launch_bounds__(256) void convw_k(
    const float* __restrict__ Wqk, const float* __restrict__ Wv,
    unsigned short* __restrict__ QTh, unsigned short* __restrict__ QTl,
    unsigned short* __restrict__ VTh, unsigned short* __restrict__ VTl)
{
    int i = blockIdx.x * 256 + threadIdx.x;          // < 786432
    float val; unsigned short *ph, *pl;
    if (i < 524288) {
        int n = i >> 9, k = i & 511;
        val = Wqk[k * 1024 + n]; ph = QTh + i; pl = QTl + i;
    } else {
        int o = i - 524288; int n = o >> 9, k = o & 511;
        val = Wv[k * 512 + n]; ph = VTh + o; pl = VTl + o;
    }
    __bf16 h = (__bf16)val;
    __bf16 l = (__bf16)(val - (float)h);
    *ph = bfbits(h); *pl = bfbits(l);
}

// ---------------------------------------------------------------------------
// MFMA GEMM: C = A @ B with B given as BT row-major [N][K].
// BM=BN=128, BK=32, 256 threads (4 waves, 2x2), 4x4 16x16x32 frags per wave.
// EPI 0: plain fp32 C. EPI 1: qk split (q fp32 / km fp32 + kmT bf16).
// NT: 1 or 3 accumulation terms (hi*hi + hi*lo + lo*hi).
// AF32: A is fp32, reg-staged + converted to bf16; else bf16 via global_load_lds.
// ---------------------------------------------------------------------------
template <int EPI, int NT, bool AF32>
__global__ __launch_bounds__(256) void mfma_gemm(
    const void* __restrict__ A0, const void* __restrict__ A1,
    const unsigned short* __restrict__ B0, const unsigned short* __restrict__ B1,
    float* __restrict__ C,
    float* __restrict__ q, float* __restrict__ km,
    unsigned short* __restrict__ kmT, const float* __restrict__ mask,
    int N, int K, long sA, long sB, long sC)
{
    __shared__ unsigned short Asm[128 * 32];
    __shared__ unsigned short Bsm[128 * 32];

    const int t = threadIdx.x;
    const int wv = t >> 6, lane = t & 63;
    const int wm = wv >> 1, wn = wv & 1;
    const int z = blockIdx.z;
    const long m0 = blockIdx.x * 128;
    const int n0 = blockIdx.y * 128;

    const unsigned short* Bz0 = B0 + (long)z * sB;
    const unsigned short* Bz1 = B1 ? B1 + (long)z * sB : nullptr;

    f32x4 acc[4][4];
#pragma unroll
    for (int i = 0; i < 4; ++i)
#pragma unroll
        for (int j = 0; j < 4; ++j) acc[i][j] = {0.f, 0.f, 0.f, 0.f};

    // frag read pointers (fixed per thread)
    const unsigned short* aP[4];
    const unsigned short* bP[4];
#pragma unroll
    for (int f = 0; f < 4; ++f) {
        aP[f] = Asm + (wm * 64 + f * 16 + (lane & 15)) * 32 + (lane >> 4) * 8;
        bP[f] = Bsm + (wn * 64 + f * 16 + (lane & 15)) * 32 + (lane >> 4) * 8;
    }

#pragma unroll 1
    for (int term = 0; term < NT; ++term) {
        const unsigned short* Ab;
        const unsigned short* Bb;
        if (NT == 3) {
            Ab = (term < 2) ? (const unsigned short*)A0 : (const unsigned short*)A1;
            Bb = (term == 1) ? Bz1 : Bz0;
        } else {
            Ab = (const unsigned short*)A0;
            Bb = Bz0;
        }
        const float* Af = AF32 ? (const float*)A0 + (long)z * sA : nullptr;

        for (int k0 = 0; k0 < K; k0 += 32) {
            __syncthreads();   // prev compute done; LDS free
            if constexpr (AF32) {
                // reg-stage + f32->bf16 convert: 128x32 tile
#pragma unroll
                for (int p = 0; p < 4; ++p) {
                    int idx4 = p * 256 + t;         // float4 idx, 0..1023
                    int row = idx4 >> 3, c4 = idx4 & 7;
                    const float4 a4 = *(const float4*)(Af + (m0 + row) * (long)K + k0 + c4 * 4);
                    __bf16 h0 = (__bf16)a4.x, h1 = (__bf16)a4.y;
                    __bf16 h2 = (__bf16)a4.z, h3 = (__bf16)a4.w;
                    ushort4 pk = make_ushort4(bfbits(h0), bfbits(h1), bfbits(h2), bfbits(h3));
                    *(ushort4*)(Asm + row * 32 + c4 * 4) = pk;
                }
            } else {
#pragma unroll
                for (int u = 0; u < 2; ++u) {
                    int c = wv + u * 4;
                    int row = c * 16 + (lane >> 2), colb = (lane & 3) * 16;
                    gll16((const char*)Ab + ((m0 + row) * (long)K + k0) * 2 + colb,
                          (char*)Asm + c * 1024);
                }
            }
#pragma unroll
            for (int u = 0; u < 2; ++u) {
                int c = wv + u * 4;
                int row = c * 16 + (lane >> 2), colb = (lane & 3) * 16;
                gll16((const char*)Bb + ((long)(n0 + row) * K + k0) * 2 + colb,
                      (char*)Bsm + c * 1024);
            }
            __syncthreads();   // staging visible

            s16x8 av[4], bv[4];
#pragma unroll
            for (int f = 0; f < 4; ++f) av[f] = *(const s16x8*)aP[f];
#pragma unroll
            for (int f = 0; f < 4; ++f) bv[f] = *(const s16x8*)bP[f];
#pragma unroll
            for (int fm = 0; fm < 4; ++fm)
#pragma unroll
                for (int fn = 0; fn < 4; ++fn)
                    acc[fm][fn] = __builtin_amdgcn_mfma_f32_16x16x32_bf16(
                        av[fm], bv[fn], acc[fm][fn], 0, 0, 0);
        }
    }

    // ---------------- epilogue ----------------
    const long rbase = m0 + wm * 64;
    const int cbase = n0 + wn * 64;

    if constexpr (EPI == 0) {
        float* Cz = C + (long)z * sC;
#pragma unroll
        for (int fm = 0; fm < 4; ++fm) {
            long rb = rbase + fm * 16 + ((lane >> 4) << 2);
#pragma unroll
            for (int fn = 0; fn < 4; ++fn) {
                int c = cbase + fn * 16 + (lane & 15);
#pragma unroll
                for (int j = 0; j < 4; ++j)
                    Cz[(rb + j) * (long)N + c] = acc[fm][fn][j];
            }
        }
    } else {
        const bool isq = (n0 < 512);
#pragma unroll
        for (int fm = 0; fm < 4; ++fm) {
            long rb = rbase + fm * 16 + ((lane >> 4) << 2);
#pragma unroll
            for (int fn = 0; fn < 4; ++fn) {
                int c = cbase + fn * 16 + (lane & 15);
                if (isq) {
#pragma unroll
                    for (int j = 0; j < 4; ++j)
                        q[(rb + j) * 512L + c] = acc[fm][fn][j];
                } else {
                    int c2 = c - 512;
                    float kv[4];
#pragma unroll
                    for (int j = 0; j < 4; ++j) {
                        kv[j] = acc[fm][fn][j] * mask[rb + j];
                        km[(rb + j) * 512L + c2] = kv[j];
                    }
                    ushort4 pk = make_ushort4(bfbits((__bf16)kv[0]), bfbits((__bf16)kv[1]),
                                              bfbits((__bf16)kv[2]), bfbits((__bf16)kv[3]));
                    long b = rb >> 13, r = rb & 8191;
                    *(ushort4*)(kmT + (b << 22) + ((long)c2 << 13) + r) = pk;
                }
            }
        }
    }
}

// ---------------------------------------------------------------------------
// w[row] = inv_scale * mask[row] * dot(q[row,:], agg[row,:])
// ---------------------------------------------------------------------------
__global__ __launch_bounds__(128) void wdot_k(
    const float* __restrict__ q, const float* __restrict__ agg,
    const float* __restrict__ mask, float* __restrict__ w)
{
    const int row = blockIdx.x;
    const int t = threadIdx.x;
    const float4 qv = ((const float4*)(q   + (long)row * 512))[t];
    const float4 av = ((const float4*)(agg + (long)row * 512))[t];
    float s = qv.x * av.x + qv.y * av.y + qv.z * av.z + qv.w * av.w;
#pragma unroll
    for (int o = 32; o > 0; o >>= 1) s += __shfl_down(s, o);
    __shared__ float red[2];
    if ((t & 63) == 0) red[t >> 6] = s;
    __syncthreads();
    if (t == 0) w[row] = (red[0] + red[1]) * INV_SCALE * mask[row];
}

// ---------------------------------------------------------------------------
// Refinement: exact fp32 recompute of w for rows near the max.
// ---------------------------------------------------------------------------
__global__ __launch_bounds__(256) void wmax_k(const float* __restrict__ w,
                                              float* __restrict__ wmax)
{
    const int b = blockIdx.x;
    const float* wr = w + (long)b * NN;
    const int t = threadIdx.x;
    float m = -3.4e38f;
    for (int i = t; i < NN; i += 256) m = fmaxf(m, wr[i]);
#pragma unroll
    for (int o = 32; o > 0; o >>= 1) m = fmaxf(m, __shfl_down(m, o));
    __shared__ float red[4];
    if ((t & 63) == 0) red[t >> 6] = m;
    __syncthreads();
    if (t == 0) wmax[b] = fmaxf(fmaxf(red[0], red[1]), fmaxf(red[2], red[3]));
}

__global__ __launch_bounds__(256) void select_k(
    const float* __restrict__ w, const float* __restrict__ wmax,
    int* __restrict__ count, int* __restrict__ cand)
{
    int i = blockIdx.x * 256 + threadIdx.x;  // 16384
    int b = i >> 13;
    if (w[i] >= wmax[b] - 15.f) {
        int p = atomicAdd(count, 1);
        if (p < 128) cand[p] = i;
    }
}

// grid (64 chunks, 128 cand slots); block 256 = 4 waves; wave handles 32 j's.
__global__ __launch_bounds__(256) void refine_k(
    const float* __restrict__ q, const float* __restrict__ km,
    const float* __restrict__ adj, const int* __restrict__ cand,
    const int* __restrict__ count, float* __restrict__ partial)
{
    int y = blockIdx.y;
    int cnt = *count; if (cnt > 128) cnt = 128;
    if (y >= cnt) return;
    const int row = cand[y];
    const int b = row >> 13, r = row & 8191;
    const int x = blockIdx.x;
    const int t = threadIdx.x, w = t >> 6, l = t & 63;

    const float* qr = q + (long)row * 512 + l * 8;
    const float4 q0 = *(const float4*)qr;
    const float4 q1 = *(const float4*)(qr + 4);
    const float* kmB = km + ((long)b << 13) * 512;
    const float* adjR = adj + (((long)b << 13) + r) * 8192L;

    float acc = 0.f;
    const int jbase = x * 128 + w * 32;
    for (int i = 0; i < 32; ++i) {
        int j = jbase + i;
        const float* kr = kmB + (long)j * 512 + l * 8;
        const float4 k0 = *(const float4*)kr;
        const float4 k1 = *(const float4*)(kr + 4);
        float d = q0.x * k0.x + q0.y * k0.y + q0.z * k0.z + q0.w * k0.w
                + q1.x * k1.x + q1.y * k1.y + q1.z * k1.z + q1.w * k1.w;
#pragma unroll
        for (int o = 32; o > 0; o >>= 1) d += __shfl_down(d, o);
        if (l == 0) acc += adjR[j] * d;
    }
    __shared__ float red[4];
    if (l == 0) red[w] = acc;
    __syncthreads();
    if (t == 0) partial[y * 64 + x] = red[0] + red[1] + red[2] + red[3];
}

__global__ __launch_bounds__(128) void apply_k(
    const int* __restrict__ cand, const int* __restrict__ count,
    const float* __restrict__ partial, const float* __restrict__ mask,
    float* __restrict__ w)
{
    int t = threadIdx.x;
    int cnt = *count; if (cnt > 128) cnt = 128;
    if (t < cnt) {
        float s = 0.f;
        for (int x = 0; x < 64; ++x) s += partial[t * 64 + x];
        int row = cand[t];
        w[row] = s * INV_SCALE * mask[row];
    }
}

// ---------------------------------------------------------------------------
__global__ __launch_bounds__(1024) void softmax_k(
    const float* __restrict__ w, float* __restrict__ p)
{
    const int b = blockIdx.x;
    const float* wr = w + (long)b * NN;
    float* pr = p + (long)b * NN;
    const int t = threadIdx.x;
    __shared__ float red[16];
    __shared__ float bmax, bsum;

    float m = -3.4e38f;
    for (int i = t; i < NN; i += 1024) m = fmaxf(m, wr[i]);
#pragma unroll
    for (int o = 32; o > 0; o >>= 1) m = fmaxf(m, __shfl_down(m, o));
    if ((t & 63) == 0) red[t >> 6] = m;
    __syncthreads();
    if (t == 0) {
        float mm = red[0];
        for (int i = 1; i < 16; ++i) mm = fmaxf(mm, red[i]);
        bmax = mm;
    }
    __syncthreads();
    const float M = bmax;

    float s = 0.f;
    for (int i = t; i < NN; i += 1024) s += expf(wr[i] - M);
#pragma unroll
    for (int o = 32; o > 0; o >>= 1) s += __shfl_down(s, o);
    __syncthreads();
    if ((t & 63) == 0) red[t >> 6] = s;
    __syncthreads();
    if (t == 0) {
        float ss = 0.f;
        for (int i = 0; i < 16; ++i) ss += red[i];
        bsum = ss;
    }
    __syncthreads();
    const float invS = 1.f / bsum;
    for (int i = t; i < NN; i += 1024) pr[i] = expf(wr[i] - M) * invS;
}

__global__ __launch_bounds__(256) void scale_k(
    const float* __restrict__ v, const float* __restrict__ p,
    float* __restrict__ out)
{
    const long i = (long)blockIdx.x * 256 + threadIdx.x;  // float4 index
    const int row = (int)(i >> 7);
    const float pv = p[row];
    float4 vv = ((const float4*)v)[i];
    vv.x *= pv; vv.y *= pv; vv.z *= pv; vv.w *= pv;
    ((float4*)out)[i] = vv;
}

// ---------------------------------------------------------------------------
extern "C" void kernel_launch(void* const* d_in, const int* in_sizes, int n_in,
                              void* d_out, int out_size, void* d_ws, size_t ws_size,
                              hipStream_t stream)
{
    const float* X    = (const float*)d_in[0];
    const float* adj  = (const float*)d_in[1];
    const float* mask = (const float*)d_in[2];
    const float* Wqk  = (const float*)d_in[3];
    const float* Wv   = (const float*)d_in[4];
    float* out = (float*)d_out;

    char* ws = (char*)d_ws;
    const long SZB = 33554432;  // 16384*512*4 bytes
    float* q_buf  = (float*)(ws);                    // 33.5 MB
    float* km_buf = (float*)(ws + SZB);              // 33.5 MB
    float* v_buf  = (float*)(ws + 2 * SZB);          // 33.5 MB
    char*  xagg   = ws + 3 * SZB;                    // 33.5 MB (Xhi|Xlo, later agg)
    unsigned short* Xhi = (unsigned short*)xagg;
    unsigned short* Xlo = (unsigned short*)(xagg + SZB / 2);
    float* agg_buf = (float*)xagg;
    unsigned short* kmT = (unsigned short*)(ws + 4 * SZB);            // 16.8 MB
    unsigned short* QTh = (unsigned short*)(ws + 4 * SZB + 16777216);
    unsigned short* QTl = QTh + 524288;
    unsigned short* VTh = QTl + 524288;
    unsigned short* VTl = VTh + 262144;
    float* w_buf = (float*)(VTl + 262144);           // 16384 f32
    float* p_buf = w_buf + 16384;
    float* wmax  = p_buf + 16384;
    float* partial = wmax + 64;                      // 128*64 f32
    int* count = (int*)(partial + 8192);
    int* cand  = count + 64;

    hipMemsetAsync(count, 0, 4, stream);

    // X -> hi/lo bf16
    convx_k<<<8192, 256, 0, stream>>>(X, Xhi, Xlo);
    // W -> transposed hi/lo bf16
    convw_k<<<3072, 256, 0, stream>>>(Wqk, Wv, QTh, QTl, VTh, VTl);

    // qk = X @ Wqk (3-term split) -> q fp32, km fp32, kmT bf16
    mfma_gemm<1, 3, false><<<dim3(128, 8, 1), 256, 0, stream>>>(
        Xhi, Xlo, QTh, QTl, nullptr, q_buf, km_buf, kmT, mask,
        1024, 512, 0, 0, 0);

    // v = X @ Wv (3-term split) -> v fp32
    mfma_gemm<0, 3, false><<<dim3(128, 4, 1), 256, 0, stream>>>(
        Xhi, Xlo, VTh, VTl, v_buf, nullptr, nullptr, nullptr, nullptr,
        512, 512, 0, 0, 0);

    // agg[b] = adj[b] @ km[b]  (bf16 MFMA, adj converted in-flight)
    mfma_gemm<0, 1, true><<<dim3(64, 4, 2), 256, 0, stream>>>(
        adj, nullptr, kmT, nullptr, agg_buf, nullptr, nullptr, nullptr, nullptr,
        512, 8192, (long)8192 * 8192, (long)512 * 8192, (long)8192 * 512);

    // w = inv_scale * mask * rowdot(q, agg)
    wdot_k<<<16384, 128, 0, stream>>>(q_buf, agg_buf, mask, w_buf);

    // exact refinement of near-max rows
    wmax_k<<<BB, 256, 0, stream>>>(w_buf, wmax);
    select_k<<<64, 256, 0, stream>>>(w_buf, wmax, count, cand);
    refine_k<<<dim3(64, 128, 1), 256, 0, stream>>>(q_buf, km_buf, adj, cand, count, partial);
    apply_k<<<1, 128, 0, stream>>>(cand, count, partial, mask, w_buf);

    // softmax + scale
    softmax_k<<<BB, 1024, 0, stream>>>(w_buf, p_buf);
    scale_k<<<8192, 256, 0, stream>>>(v_buf, p_buf, out);
}

// Round 3
// 458.190 us; speedup vs baseline: 4.4420x; 1.2085x over previous
//
#include <hip/hip_runtime.h>
#include <math.h>

#define BB 2
#define NN 8192
#define DD 512

static const float INV_SCALE = 0.04419417382415922f; // 1/sqrt(512)

typedef short s16x8 __attribute__((ext_vector_type(8)));
typedef unsigned short u16x8 __attribute__((ext_vector_type(8)));
typedef float f32x4 __attribute__((ext_vector_type(4)));

#define AS1 __attribute__((address_space(1)))
#define AS3 __attribute__((address_space(3)))

__device__ __forceinline__ unsigned short bfbits(__bf16 h) {
    return __builtin_bit_cast(unsigned short, h);
}

__device__ __forceinline__ void gll16(const void* g, void* l) {
    __builtin_amdgcn_global_load_lds((const AS1 unsigned int*)g, (AS3 unsigned int*)l, 16, 0, 0);
}

// ---------------------------------------------------------------------------
// convX: X f32 -> Xhi, Xlo bf16 (hi = rne(x), lo = rne(x - hi))
// ---------------------------------------------------------------------------
__global__ __launch_bounds__(256) void convx_k(
    const float* __restrict__ X, unsigned short* __restrict__ Xhi,
    unsigned short* __restrict__ Xlo)
{
    long i = (long)blockIdx.x * 256 + threadIdx.x;   // float4 index
    float4 x = ((const float4*)X)[i];
    __bf16 h0 = (__bf16)x.x, h1 = (__bf16)x.y, h2 = (__bf16)x.z, h3 = (__bf16)x.w;
    ushort4 hi4 = make_ushort4(bfbits(h0), bfbits(h1), bfbits(h2), bfbits(h3));
    __bf16 l0 = (__bf16)(x.x - (float)h0), l1 = (__bf16)(x.y - (float)h1);
    __bf16 l2 = (__bf16)(x.z - (float)h2), l3 = (__bf16)(x.w - (float)h3);
    ushort4 lo4 = make_ushort4(bfbits(l0), bfbits(l1), bfbits(l2), bfbits(l3));
    ((ushort4*)Xhi)[i] = hi4;
    ((ushort4*)Xlo)[i] = lo4;
}

// ---------------------------------------------------------------------------
// convW: Wqk (512x1024) -> WqkT hi/lo (1024x512 bf16); Wv (512x512) -> WvT hi/lo
// ---------------------------------------------------------------------------
__global__ __launch_bounds__(256) void convw_k(
    const float* __restrict__ Wqk, const float* __restrict__ Wv,
    unsigned short* __restrict__ QTh, unsigned short* __restrict__ QTl,
    unsigned short* __restrict__ VTh, unsigned short* __restrict__ VTl)
{
    int i = blockIdx.x * 256 + threadIdx.x;          // < 786432
    float val; unsigned short *ph, *pl;
    if (i < 524288) {
        int n = i >> 9, k = i & 511;
        val = Wqk[k * 1024 + n]; ph = QTh + i; pl = QTl + i;
    } else {
        int o = i - 524288; int n = o >> 9, k = o & 511;
        val = Wv[k * 512 + n]; ph = VTh + o; pl = VTl + o;
    }
    __bf16 h = (__bf16)val;
    __bf16 l = (__bf16)(val - (float)h);
    *ph = bfbits(h); *pl = bfbits(l);
}

// ---------------------------------------------------------------------------
// Pipelined MFMA GEMM: C = A @ B, B given transposed [N][K] bf16.
// BM=BN=128, 256 threads (4 waves 2x2), 4x4 16x16x32 frags/wave.
// Double-buffered LDS, ONE barrier per K-step (stage t+1 || compute t).
// AF32: A fp32, reg-staged (issue early, cvt+ds_write late). Requires BK=64.
// NT: 1 or 3 terms (hi*hi + hi*lo + lo*hi), flattened into the tile loop.
// EPI 0: fp32 C. EPI 1: qk split (q fp32 / km fp32 + kmT bf16).
// ---------------------------------------------------------------------------
template <int EPI, int NT, bool AF32, int BK>
__global__ __launch_bounds__(256) void mfma_gemm(
    const void* __restrict__ A0, const void* __restrict__ A1,
    const unsigned short* __restrict__ B0, const unsigned short* __restrict__ B1,
    float* __restrict__ C,
    float* __restrict__ q, float* __restrict__ km,
    unsigned short* __restrict__ kmT, const float* __restrict__ mask,
    int N, int K, long sA, long sB, long sC)
{
    constexpr int TILE_SH = 128 * BK;        // shorts per buffer
    constexpr int KS  = BK / 32;             // MFMA k-substeps per tile
    constexpr int CPW = BK / 16;             // 1KB gll16 chunks per wave
    constexpr int RPC = 512 / BK;            // rows per 1KB chunk
    constexpr int LPR = BK / 8;              // lanes per row (gll16)

    __shared__ unsigned short Asm[2 * TILE_SH];
    __shared__ unsigned short Bsm[2 * TILE_SH];

    const int t = threadIdx.x;
    const int wv = t >> 6, lane = t & 63;
    const int wm = wv >> 1, wn = wv & 1;
    const int z = blockIdx.z;
    const long m0 = blockIdx.x * 128;
    const int n0 = blockIdx.y * 128;

    const unsigned short* Bz0 = B0 + (long)z * sB;
    const unsigned short* Bz1 = B1 ? B1 + (long)z * sB : nullptr;
    const float* Af = AF32 ? (const float*)A0 + (long)z * sA : nullptr;

    f32x4 acc[4][4];
#pragma unroll
    for (int i = 0; i < 4; ++i)
#pragma unroll
        for (int j = 0; j < 4; ++j) acc[i][j] = {0.f, 0.f, 0.f, 0.f};

    float4 rA[8];   // AF32 staging registers (tile t+1 in flight)

    auto issueA = [&](int k0) {              // AF32 only (BK=64)
#pragma unroll
        for (int p = 0; p < 4; ++p) {
            int idx8 = p * 256 + t;          // ushort8-chunk index
            int row = idx8 >> 3, c8 = idx8 & 7;
            const float* s = Af + (m0 + row) * (long)K + k0 + c8 * 8;
            rA[2 * p]     = *(const float4*)s;
            rA[2 * p + 1] = *(const float4*)(s + 4);
        }
    };
    auto commitA = [&](int buf) {            // cvt + ds_write (waits rA vmcnt)
#pragma unroll
        for (int p = 0; p < 4; ++p) {
            int idx8 = p * 256 + t;
            int row = idx8 >> 3, c8 = idx8 & 7;
            float4 a = rA[2 * p], b = rA[2 * p + 1];
            u16x8 pk;
            pk[0] = bfbits((__bf16)a.x); pk[1] = bfbits((__bf16)a.y);
            pk[2] = bfbits((__bf16)a.z); pk[3] = bfbits((__bf16)a.w);
            pk[4] = bfbits((__bf16)b.x); pk[5] = bfbits((__bf16)b.y);
            pk[6] = bfbits((__bf16)b.z); pk[7] = bfbits((__bf16)b.w);
            *(u16x8*)(Asm + buf * TILE_SH + row * BK + c8 * 8) = pk;
        }
    };
    auto stageA16 = [&](int term, int k0, int buf) {
        const unsigned short* Ab = (term < 2) ? (const unsigned short*)A0
                                              : (const unsigned short*)A1;
#pragma unroll
        for (int u = 0; u < CPW; ++u) {
            int c = wv * CPW + u;
            int row = c * RPC + lane / LPR;
            int colb = (lane % LPR) * 16;
            gll16((const char*)Ab + ((m0 + row) * (long)K + k0) * 2 + colb,
                  (char*)Asm + buf * (TILE_SH * 2) + c * 1024);
        }
    };
    auto stageB16 = [&](int term, int k0, int buf) {
        const unsigned short* Bb = (NT == 3 && term == 1) ? Bz1 : Bz0;
#pragma unroll
        for (int u = 0; u < CPW; ++u) {
            int c = wv * CPW + u;
            int row = c * RPC + lane / LPR;
            int colb = (lane % LPR) * 16;
            gll16((const char*)Bb + ((long)(n0 + row) * K + k0) * 2 + colb,
                  (char*)Bsm + buf * (TILE_SH * 2) + c * 1024);
        }
    };

    // ---- prologue: stage tile 0 into buf 0 ----
    if constexpr (AF32) {
        issueA(0);
        stageB16(0, 0, 0);
        commitA(0);
    } else {
        stageA16(0, 0, 0);
        stageB16(0, 0, 0);
    }
    __syncthreads();

    const int NTILES = NT * (K / BK);
    int cur = 0, term = 0, k0 = 0;

#pragma unroll 2
    for (int tt = 0; tt < NTILES; ++tt) {
        int k0n = k0 + BK, termn = term;
        if (k0n == K) { k0n = 0; ++termn; }
        const bool hasNext = (tt + 1 < NTILES);

        // stage tile t+1 into the other buffer (loads issued before compute)
        if (hasNext) {
            if constexpr (AF32) issueA(k0n);
            else stageA16(termn, k0n, cur ^ 1);
            stageB16(termn, k0n, cur ^ 1);
        }

        // compute tile t from buf[cur]
        const int koff = (lane >> 4) * 8;
#pragma unroll
        for (int ks = 0; ks < KS; ++ks) {
            s16x8 av[4], bv[4];
#pragma unroll
            for (int f = 0; f < 4; ++f) {
                av[f] = *(const s16x8*)(Asm + cur * TILE_SH
                        + (wm * 64 + f * 16 + (lane & 15)) * BK + koff + ks * 32);
                bv[f] = *(const s16x8*)(Bsm + cur * TILE_SH
                        + (wn * 64 + f * 16 + (lane & 15)) * BK + koff + ks * 32);
            }
#pragma unroll
            for (int fm = 0; fm < 4; ++fm)
#pragma unroll
                for (int fn = 0; fn < 4; ++fn)
                    acc[fm][fn] = __builtin_amdgcn_mfma_f32_16x16x32_bf16(
                        av[fm], bv[fn], acc[fm][fn], 0, 0, 0);
        }

        // late A-commit: vmcnt wait on rA hidden under the MFMA above
        if (AF32 && hasNext) commitA(cur ^ 1);

        __syncthreads();
        cur ^= 1; term = termn; k0 = k0n;
    }

    // ---------------- epilogue ----------------
    const long rbase = m0 + wm * 64;
    const int cbase = n0 + wn * 64;

    if constexpr (EPI == 0) {
        float* Cz = C + (long)z * sC;
#pragma unroll
        for (int fm = 0; fm < 4; ++fm) {
            long rb = rbase + fm * 16 + ((lane >> 4) << 2);
#pragma unroll
            for (int fn = 0; fn < 4; ++fn) {
                int c = cbase + fn * 16 + (lane & 15);
#pragma unroll
                for (int j = 0; j < 4; ++j)
                    Cz[(rb + j) * (long)N + c] = acc[fm][fn][j];
            }
        }
    } else {
        const bool isq = (n0 < 512);
#pragma unroll
        for (int fm = 0; fm < 4; ++fm) {
            long rb = rbase + fm * 16 + ((lane >> 4) << 2);
#pragma unroll
            for (int fn = 0; fn < 4; ++fn) {
                int c = cbase + fn * 16 + (lane & 15);
                if (isq) {
#pragma unroll
                    for (int j = 0; j < 4; ++j)
                        q[(rb + j) * 512L + c] = acc[fm][fn][j];
                } else {
                    int c2 = c - 512;
                    float kv[4];
#pragma unroll
                    for (int j = 0; j < 4; ++j) {
                        kv[j] = acc[fm][fn][j] * mask[rb + j];
                        km[(rb + j) * 512L + c2] = kv[j];
                    }
                    ushort4 pk = make_ushort4(bfbits((__bf16)kv[0]), bfbits((__bf16)kv[1]),
                                              bfbits((__bf16)kv[2]), bfbits((__bf16)kv[3]));
                    long b = rb >> 13, r = rb & 8191;
                    *(ushort4*)(kmT + (b << 22) + ((long)c2 << 13) + r) = pk;
                }
            }
        }
    }
}

// ---------------------------------------------------------------------------
// w[row] = inv_scale * mask[row] * dot(q[row,:], agg[row,:])
// ---------------------------------------------------------------------------
__global__ __launch_bounds__(128) void wdot_k(
    const float* __restrict__ q, const float* __restrict__ agg,
    const float* __restrict__ mask, float* __restrict__ w)
{
    const int row = blockIdx.x;
    const int t = threadIdx.x;
    const float4 qv = ((const float4*)(q   + (long)row * 512))[t];
    const float4 av = ((const float4*)(agg + (long)row * 512))[t];
    float s = qv.x * av.x + qv.y * av.y + qv.z * av.z + qv.w * av.w;
#pragma unroll
    for (int o = 32; o > 0; o >>= 1) s += __shfl_down(s, o);
    __shared__ float red[2];
    if ((t & 63) == 0) red[t >> 6] = s;
    __syncthreads();
    if (t == 0) w[row] = (red[0] + red[1]) * INV_SCALE * mask[row];
}

// ---------------------------------------------------------------------------
// Refinement: exact fp32 recompute of w for rows near the max.
// ---------------------------------------------------------------------------
__global__ __launch_bounds__(256) void wmax_k(const float* __restrict__ w,
                                              float* __restrict__ wmax)
{
    const int b = blockIdx.x;
    const float* wr = w + (long)b * NN;
    const int t = threadIdx.x;
    float m = -3.4e38f;
    for (int i = t; i < NN; i += 256) m = fmaxf(m, wr[i]);
#pragma unroll
    for (int o = 32; o > 0; o >>= 1) m = fmaxf(m, __shfl_down(m, o));
    __shared__ float red[4];
    if ((t & 63) == 0) red[t >> 6] = m;
    __syncthreads();
    if (t == 0) wmax[b] = fmaxf(fmaxf(red[0], red[1]), fmaxf(red[2], red[3]));
}

__global__ __launch_bounds__(256) void select_k(
    const float* __restrict__ w, const float* __restrict__ wmax,
    int* __restrict__ count, int* __restrict__ cand)
{
    int i = blockIdx.x * 256 + threadIdx.x;  // 16384
    int b = i >> 13;
    if (w[i] >= wmax[b] - 15.f) {
        int p = atomicAdd(count, 1);
        if (p < 128) cand[p] = i;
    }
}

__global__ __launch_bounds__(256) void refine_k(
    const float* __restrict__ q, const float* __restrict__ km,
    const float* __restrict__ adj, const int* __restrict__ cand,
    const int* __restrict__ count, float* __restrict__ partial)
{
    int y = blockIdx.y;
    int cnt = *count; if (cnt > 128) cnt = 128;
    if (y >= cnt) return;
    const int row = cand[y];
    const int b = row >> 13, r = row & 8191;
    const int x = blockIdx.x;
    const int t = threadIdx.x, w = t >> 6, l = t & 63;

    const float* qr = q + (long)row * 512 + l * 8;
    const float4 q0 = *(const float4*)qr;
    const float4 q1 = *(const float4*)(qr + 4);
    const float* kmB = km + ((long)b << 13) * 512;
    const float* adjR = adj + (((long)b << 13) + r) * 8192L;

    float acc = 0.f;
    const int jbase = x * 128 + w * 32;
    for (int i = 0; i < 32; ++i) {
        int j = jbase + i;
        const float* kr = kmB + (long)j * 512 + l * 8;
        const float4 k0 = *(const float4*)kr;
        const float4 k1 = *(const float4*)(kr + 4);
        float d = q0.x * k0.x + q0.y * k0.y + q0.z * k0.z + q0.w * k0.w
                + q1.x * k1.x + q1.y * k1.y + q1.z * k1.z + q1.w * k1.w;
#pragma unroll
        for (int o = 32; o > 0; o >>= 1) d += __shfl_down(d, o);
        if (l == 0) acc += adjR[j] * d;
    }
    __shared__ float red[4];
    if (l == 0) red[w] = acc;
    __syncthreads();
    if (t == 0) partial[y * 64 + x] = red[0] + red[1] + red[2] + red[3];
}

__global__ __launch_bounds__(128) void apply_k(
    const int* __restrict__ cand, const int* __restrict__ count,
    const float* __restrict__ partial, const float* __restrict__ mask,
    float* __restrict__ w)
{
    int t = threadIdx.x;
    int cnt = *count; if (cnt > 128) cnt = 128;
    if (t < cnt) {
        float s = 0.f;
        for (int x = 0; x < 64; ++x) s += partial[t * 64 + x];
        int row = cand[t];
        w[row] = s * INV_SCALE * mask[row];
    }
}

// ---------------------------------------------------------------------------
__global__ __launch_bounds__(1024) void softmax_k(
    const float* __restrict__ w, float* __restrict__ p)
{
    const int b = blockIdx.x;
    const float* wr = w + (long)b * NN;
    float* pr = p + (long)b * NN;
    const int t = threadIdx.x;
    __shared__ float red[16];
    __shared__ float bmax, bsum;

    float m = -3.4e38f;
    for (int i = t; i < NN; i += 1024) m = fmaxf(m, wr[i]);
#pragma unroll
    for (int o = 32; o > 0; o >>= 1) m = fmaxf(m, __shfl_down(m, o));
    if ((t & 63) == 0) red[t >> 6] = m;
    __syncthreads();
    if (t == 0) {
        float mm = red[0];
        for (int i = 1; i < 16; ++i) mm = fmaxf(mm, red[i]);
        bmax = mm;
    }
    __syncthreads();
    const float M = bmax;

    float s = 0.f;
    for (int i = t; i < NN; i += 1024) s += expf(wr[i] - M);
#pragma unroll
    for (int o = 32; o > 0; o >>= 1) s += __shfl_down(s, o);
    __syncthreads();
    if ((t & 63) == 0) red[t >> 6] = s;
    __syncthreads();
    if (t == 0) {
        float ss = 0.f;
        for (int i = 0; i < 16; ++i) ss += red[i];
        bsum = ss;
    }
    __syncthreads();
    const float invS = 1.f / bsum;
    for (int i = t; i < NN; i += 1024) pr[i] = expf(wr[i] - M) * invS;
}

__global__ __launch_bounds__(256) void scale_k(
    const float* __restrict__ v, const float* __restrict__ p,
    float* __restrict__ out)
{
    const long i = (long)blockIdx.x * 256 + threadIdx.x;  // float4 index
    const int row = (int)(i >> 7);
    const float pv = p[row];
    float4 vv = ((const float4*)v)[i];
    vv.x *= pv; vv.y *= pv; vv.z *= pv; vv.w *= pv;
    ((float4*)out)[i] = vv;
}

// ---------------------------------------------------------------------------
extern "C" void kernel_launch(void* const* d_in, const int* in_sizes, int n_in,
                              void* d_out, int out_size, void* d_ws, size_t ws_size,
                              hipStream_t stream)
{
    const float* X    = (const float*)d_in[0];
    const float* adj  = (const float*)d_in[1];
    const float* mask = (const float*)d_in[2];
    const float* Wqk  = (const float*)d_in[3];
    const float* Wv   = (const float*)d_in[4];
    float* out = (float*)d_out;

    char* ws = (char*)d_ws;
    const long SZB = 33554432;  // 16384*512*4 bytes
    float* q_buf  = (float*)(ws);
    float* km_buf = (float*)(ws + SZB);
    float* v_buf  = (float*)(ws + 2 * SZB);
    char*  xagg   = ws + 3 * SZB;                    // Xhi|Xlo, later agg
    unsigned short* Xhi = (unsigned short*)xagg;
    unsigned short* Xlo = (unsigned short*)(xagg + SZB / 2);
    float* agg_buf = (float*)xagg;
    unsigned short* kmT = (unsigned short*)(ws + 4 * SZB);
    unsigned short* QTh = (unsigned short*)(ws + 4 * SZB + 16777216);
    unsigned short* QTl = QTh + 524288;
    unsigned short* VTh = QTl + 524288;
    unsigned short* VTl = VTh + 262144;
    float* w_buf = (float*)(VTl + 262144);
    float* p_buf = w_buf + 16384;
    float* wmax  = p_buf + 16384;
    float* partial = wmax + 64;
    int* count = (int*)(partial + 8192);
    int* cand  = count + 64;

    hipMemsetAsync(count, 0, 4, stream);

    convx_k<<<8192, 256, 0, stream>>>(X, Xhi, Xlo);
    convw_k<<<3072, 256, 0, stream>>>(Wqk, Wv, QTh, QTl, VTh, VTl);

    // qk = X @ Wqk (3-term split) -> q fp32, km fp32, kmT bf16
    mfma_gemm<1, 3, false, 32><<<dim3(128, 8, 1), 256, 0, stream>>>(
        Xhi, Xlo, QTh, QTl, nullptr, q_buf, km_buf, kmT, mask,
        1024, 512, 0, 0, 0);

    // v = X @ Wv (3-term split)
    mfma_gemm<0, 3, false, 32><<<dim3(128, 4, 1), 256, 0, stream>>>(
        Xhi, Xlo, VTh, VTl, v_buf, nullptr, nullptr, nullptr, nullptr,
        512, 512, 0, 0, 0);

    // agg[b] = adj[b] @ km[b]  (bf16 MFMA, adj converted in-flight, pipelined)
    mfma_gemm<0, 1, true, 64><<<dim3(64, 4, 2), 256, 0, stream>>>(
        adj, nullptr, kmT, nullptr, agg_buf, nullptr, nullptr, nullptr, nullptr,
        512, 8192, (long)8192 * 8192, (long)512 * 8192, (long)8192 * 512);

    wdot_k<<<16384, 128, 0, stream>>>(q_buf, agg_buf, mask, w_buf);

    wmax_k<<<BB, 256, 0, stream>>>(w_buf, wmax);
    select_k<<<64, 256, 0, stream>>>(w_buf, wmax, count, cand);
    refine_k<<<dim3(64, 128, 1), 256, 0, stream>>>(q_buf, km_buf, adj, cand, count, partial);
    apply_k<<<1, 128, 0, stream>>>(cand, count, partial, mask, w_buf);

    softmax_k<<<BB, 1024, 0, stream>>>(w_buf, p_buf);
    scale_k<<<8192, 256, 0, stream>>>(v_buf, p_buf, out);
}